// Round 2
// baseline (1356.155 us; speedup 1.0000x reference)
//
#include <hip/hip_runtime.h>

// Problem constants (from reference setup_inputs)
#define NB   4096   // batch
#define NE   20     // electrons
#define NA   4      // atoms
#define HE   256
#define HEE  32
#define NUPC 10
#define FIN  832    // 3*HE + 2*HEE
#define IN0  56     // (3*NA+2)*(NDIM+1)

typedef short short8v __attribute__((ext_vector_type(8)));
typedef float f32x4  __attribute__((ext_vector_type(4)));

__device__ __forceinline__ float fast_tanh(float x){
    float e = __expf(-2.f*fabsf(x));
    float r = (1.f - e) / (1.f + e);
    return copysignf(r, x);
}

// fp32 -> bf16 round-to-nearest-even (bit pattern as ushort)
__device__ __forceinline__ unsigned short f2bf(float x){
    unsigned int u = __float_as_uint(x);
    u += 0x7FFFu + ((u >> 16) & 1u);
    return (unsigned short)(u >> 16);
}

__device__ __forceinline__ void gload16(const void* g, void* l){
    __builtin_amdgcn_global_load_lds(
        (const __attribute__((address_space(1))) void*)g,
        (__attribute__((address_space(3))) void*)l, 16, 0, 0);
}

// ---------------------------------------------------------------------------
// Convert + transpose We_rest [3][832][256] f32  ->  Wt [3][256][832] bf16
// ---------------------------------------------------------------------------
__global__ __launch_bounds__(256) void k_wconv(const float* __restrict__ W,
                                               unsigned short* __restrict__ Wt){
    int idx = blockIdx.x*256 + threadIdx.x;
    if (idx >= 3*832*256) return;
    int l = idx / (832*256);
    int rem = idx - l*(832*256);
    int k = rem >> 8, c = rem & 255;
    Wt[(size_t)l*212992 + (size_t)c*832 + k] = f2bf(W[idx]);
}

// ---------------------------------------------------------------------------
// Layer 0: build h_i0 (16), h_ij0 (4), means, f0 (56); apply both layer-0
// linears (K small -> fp32 VALU). One block per batch element b.
// ---------------------------------------------------------------------------
__global__ __launch_bounds__(256) void k_layer0(
    const float* __restrict__ pos, const float* __restrict__ rnuc,
    const float* __restrict__ We0, const float* __restrict__ be0,
    const float* __restrict__ Wee0, const float* __restrict__ bee0,
    float* __restrict__ hi, float* __restrict__ hij)
{
    __shared__ float ps[NE][3];
    __shared__ float rn[NA][3];
    __shared__ float f0[NE][IN0];
    __shared__ float h0[NE][NE][4];
    __shared__ float Ws[4][32];
    __shared__ float bs[32];
    int b = blockIdx.x, t = threadIdx.x;
    if (t < 60)               ps[t/3][t%3] = pos[b*60 + t];
    if (t >= 64 && t < 76)    rn[(t-64)/3][(t-64)%3] = rnuc[t-64];
    if (t >= 96 && t < 128)   bs[t-96] = bee0[t-96];
    if (t >= 128 && t < 256)  Ws[(t-128)>>5][(t-128)&31] = Wee0[t-128];
    __syncthreads();
    if (t < 80){
        int n = t >> 2, a = t & 3;
        float dx = ps[n][0]-rn[a][0], dy = ps[n][1]-rn[a][1], dz = ps[n][2]-rn[a][2];
        f0[n][a*4+0] = dx; f0[n][a*4+1] = dy; f0[n][a*4+2] = dz;
        f0[n][a*4+3] = sqrtf(dx*dx + dy*dy + dz*dz);
    }
    for (int q = t; q < 400; q += 256){
        int i = q/20, j = q - 20*(q/20);
        float dx = ps[i][0]-ps[j][0], dy = ps[i][1]-ps[j][1], dz = ps[i][2]-ps[j][2];
        float sq = dx*dx + dy*dy + dz*dz;
        h0[i][j][0] = dx; h0[i][j][1] = dy; h0[i][j][2] = dz;
        h0[i][j][3] = sq > 0.f ? sqrtf(sq) : 0.f;   // _safe_norm: exact 0 when i==j
    }
    __syncthreads();
    // spin means of h_i0 -> f0 cols 16..47
    for (int q = t; q < 320; q += 256){
        int n = q >> 4, m = q & 15;
        float sd = 0.f, su = 0.f;
        #pragma unroll
        for (int i = 0; i < 10; i++)  sd += f0[i][m];
        #pragma unroll
        for (int i = 10; i < 20; i++) su += f0[i][m];
        f0[n][16+m] = sd*0.1f; f0[n][32+m] = su*0.1f;
    }
    // ee means over i -> f0 cols 48..55
    if (t < 80){
        int n = t >> 2, c = t & 3;
        float sd = 0.f, su = 0.f;
        #pragma unroll
        for (int i = 0; i < 10; i++)  sd += h0[i][n][c];
        #pragma unroll
        for (int i = 10; i < 20; i++) su += h0[i][n][c];
        f0[n][48+c] = sd*0.1f; f0[n][52+c] = su*0.1f;
    }
    __syncthreads();
    // ee linear 0: [400,4]@[4,32], tanh, no residual (4 != 32)
    float* hb = hij + (size_t)b*12800;
    for (int q = t; q < 12800; q += 256){
        int r = q >> 5, c = q & 31;
        int i = r/20, j = r - 20*(r/20);
        float acc = bs[c];
        #pragma unroll
        for (int k = 0; k < 4; k++) acc += h0[i][j][k]*Ws[k][c];
        hb[q] = fast_tanh(acc);
    }
    // hi linear 0: [20,56]@[56,256], tanh, no residual (56 != 256)
    {
        int c = t;
        float wcol[IN0];
        #pragma unroll
        for (int k = 0; k < IN0; k++) wcol[k] = We0[k*256 + c];
        float bias = be0[c];
        float* ob = hi + (size_t)b*5120 + c;
        for (int n = 0; n < NE; n++){
            float acc = bias;
            #pragma unroll
            for (int k = 0; k < IN0; k++) acc += f0[n][k]*wcol[k];
            ob[n*256] = fast_tanh(acc);
        }
    }
}

// ---------------------------------------------------------------------------
// Spin means of h_i: gm[b][0..255]=mean(i<10), gm[b][256..511]=mean(i>=10)
// ---------------------------------------------------------------------------
__global__ __launch_bounds__(256) void k_means_hi(const float* __restrict__ hi,
                                                  float* __restrict__ gm){
    int b = blockIdx.x, c = threadIdx.x;
    const float* p = hi + (size_t)b*5120 + c;
    float sd = 0.f, su = 0.f;
    #pragma unroll
    for (int i = 0; i < 10; i++)  sd += p[i*256];
    #pragma unroll
    for (int i = 10; i < 20; i++) su += p[i*256];
    gm[b*512 + c]       = sd*0.1f;
    gm[b*512 + 256 + c] = su*0.1f;
}

// ---------------------------------------------------------------------------
// ee path, layers 1..3: eem = means over i of CURRENT h_ij; then in-place
// h_ij = tanh(h_ij @ Wee + bee) + h_ij.  One block per b; h_ij[b] in LDS.
// ---------------------------------------------------------------------------
__global__ __launch_bounds__(256) void k_ee(const float* __restrict__ hij,
    const float* __restrict__ Wee, const float* __restrict__ bee,
    float* __restrict__ out, float* __restrict__ eem)
{
    __shared__ float hs[12800];   // [i][j][c] = [(i*20+j)*32+c]
    __shared__ float Ws[1024];    // [k][c]
    __shared__ float bs[32];
    int b = blockIdx.x, t = threadIdx.x;
    const float4* src = (const float4*)(hij + (size_t)b*12800);
    float4* hs4 = (float4*)hs;
    for (int q = t; q < 3200; q += 256) hs4[q] = src[q];
    for (int q = t; q < 1024; q += 256) Ws[q] = Wee[q];
    if (t < 32) bs[t] = bee[t];
    __syncthreads();
    // means over i (pre-update values)
    for (int q = t; q < 640; q += 256){
        int j = q >> 5, c = q & 31;
        float sd = 0.f, su = 0.f;
        #pragma unroll
        for (int i = 0; i < 10; i++)  sd += hs[(i*20+j)*32 + c];
        #pragma unroll
        for (int i = 10; i < 20; i++) su += hs[(i*20+j)*32 + c];
        eem[b*1280 + j*64 + c]      = sd*0.1f;
        eem[b*1280 + j*64 + 32 + c] = su*0.1f;
    }
    // update (block owns b entirely -> in-place safe)
    float* outb = out + (size_t)b*12800;
    for (int q = t; q < 12800; q += 256){
        int r = q >> 5, c = q & 31;       // lanes 0..31 share r (broadcast reads)
        const float* row = &hs[r*32];
        float acc = bs[c];
        #pragma unroll
        for (int k = 0; k < 32; k++) acc += row[k]*Ws[k*32 + c];
        outb[q] = fast_tanh(acc) + row[c];
    }
}

// ---------------------------------------------------------------------------
// Build f (bf16) rows: [h_i(256) | g_down(256) | g_up(256) | eem_dn(32) | eem_up(32)]
// One thread per 4 consecutive columns (region boundaries are all %4==0).
// ---------------------------------------------------------------------------
__global__ __launch_bounds__(256) void k_fbuild(const float* __restrict__ hi,
    const float* __restrict__ gm, const float* __restrict__ eem,
    unsigned short* __restrict__ f)
{
    int idx = blockIdx.x*256 + threadIdx.x;   // 81920*208 total, grid exact
    int rw = idx / 208, c4 = idx - rw*208;
    int b = rw / 20, n = rw - b*20;
    int k0 = c4*4;
    const float* src;
    if      (k0 < 256) src = hi  + (size_t)rw*256 + k0;
    else if (k0 < 512) src = gm  + b*512 + (k0-256);
    else if (k0 < 768) src = gm  + b*512 + 256 + (k0-512);
    else if (k0 < 800) src = eem + b*1280 + n*64 + (k0-768);
    else               src = eem + b*1280 + n*64 + 32 + (k0-800);
    float4 v = *(const float4*)src;
    uint2 o;
    o.x = (unsigned)f2bf(v.x) | ((unsigned)f2bf(v.y) << 16);
    o.y = (unsigned)f2bf(v.z) | ((unsigned)f2bf(v.w) << 16);
    *(uint2*)(f + (size_t)idx*4) = o;
}

// ---------------------------------------------------------------------------
// Main GEMM (layers 1..3): h_i = tanh(f @ W + be) + h_i
// M=81920, K=832, N=256. bf16 MFMA 16x16x32, 128x128 tile, BK=32,
// 4 waves of 64x64. A = f [M][832] bf16, B = Wt [256][832] bf16 (pre-transposed).
// ---------------------------------------------------------------------------
__global__ __launch_bounds__(256) void k_gemm_hi(
    const unsigned short* __restrict__ f, const unsigned short* __restrict__ Wt,
    const float* __restrict__ be, float* __restrict__ hi)
{
    __shared__ unsigned short As[128*32];   // [row][k] 8KB
    __shared__ unsigned short Bs[128*32];   // [col][k] 8KB
    int t = threadIdx.x;
    int wave = t >> 6, lane = t & 63;
    int mtile = blockIdx.x >> 1, ntile = blockIdx.x & 1;
    int wr = wave >> 1, wc = wave & 1;
    f32x4 acc[4][4] = {};
    const unsigned short* fbase = f  + (size_t)mtile*128*832;
    const unsigned short* wbase = Wt + (size_t)ntile*128*832;
    int off0 = wave*1024 + lane*16;         // byte offset pattern for staging
    int rl = lane & 15, kq = (lane >> 4)*8;
    for (int ks = 0; ks < 26; ks++){
        int kb = ks*32;
        #pragma unroll
        for (int q = 0; q < 2; q++){
            int off = off0 + q*4096;
            int row = off >> 6, ch = (off & 63) >> 4;
            gload16(fbase + (size_t)row*832 + kb + ch*8, (char*)As + off);
            gload16(wbase + (size_t)row*832 + kb + ch*8, (char*)Bs + off);
        }
        asm volatile("s_waitcnt vmcnt(0)" ::: "memory");
        __syncthreads();
        short8v af[4], bfr[4];
        #pragma unroll
        for (int m = 0; m < 4; m++)
            af[m] = *(const short8v*)(As + (wr*64 + m*16 + rl)*32 + kq);
        #pragma unroll
        for (int n = 0; n < 4; n++)
            bfr[n] = *(const short8v*)(Bs + (wc*64 + n*16 + rl)*32 + kq);
        #pragma unroll
        for (int m = 0; m < 4; m++)
            #pragma unroll
            for (int n = 0; n < 4; n++)
                acc[m][n] = __builtin_amdgcn_mfma_f32_16x16x32_bf16(af[m], bfr[n], acc[m][n], 0, 0, 0);
        __syncthreads();
    }
    // epilogue: C/D layout col=lane&15, row=(lane>>4)*4+r
    int rq = lane >> 4;
    #pragma unroll
    for (int m = 0; m < 4; m++){
        int rowb = mtile*128 + wr*64 + m*16 + rq*4;
        #pragma unroll
        for (int n = 0; n < 4; n++){
            int col = ntile*128 + wc*64 + n*16 + rl;
            float bias = be[col];
            #pragma unroll
            for (int r = 0; r < 4; r++){
                size_t o = (size_t)(rowb + r)*256 + col;
                hi[o] = fast_tanh(acc[m][n][r] + bias) + hi[o];   // residual, in-place
            }
        }
    }
}

// ---------------------------------------------------------------------------
extern "C" void kernel_launch(void* const* d_in, const int* in_sizes, int n_in,
                              void* d_out, int out_size, void* d_ws, size_t ws_size,
                              hipStream_t stream)
{
    const float* pos  = (const float*)d_in[0];
    const float* rnuc = (const float*)d_in[1];
    const float* We0  = (const float*)d_in[2];
    const float* be0  = (const float*)d_in[3];
    const float* Wer  = (const float*)d_in[4];   // [3][832][256]
    const float* ber  = (const float*)d_in[5];   // [3][256]
    const float* Wee0 = (const float*)d_in[6];
    const float* bee0 = (const float*)d_in[7];
    const float* Weer = (const float*)d_in[8];   // [3][32][32]
    const float* beer = (const float*)d_in[9];   // [3][32]

    float* hi  = (float*)d_out;                     // [81920][256]
    float* hij = (float*)d_out + (size_t)81920*256; // [4096][20][20][32]

    char* w = (char*)d_ws;
    float* gm  = (float*)w;                              // 4096*512*4   = 8,388,608 B
    float* eem = (float*)(w + 8388608);                  // 4096*1280*4  = 20,971,520 B
    unsigned short* f  = (unsigned short*)(w + 29360128);   // 81920*832*2 = 136,314,880 B
    unsigned short* Wt = (unsigned short*)(w + 165675008);  // 3*256*832*2 = 1,277,952 B

    hipLaunchKernelGGL(k_wconv, dim3(2496), dim3(256), 0, stream, Wer, Wt);
    hipLaunchKernelGGL(k_layer0, dim3(NB), dim3(256), 0, stream,
                       pos, rnuc, We0, be0, Wee0, bee0, hi, hij);
    for (int l = 1; l < 4; l++){
        hipLaunchKernelGGL(k_means_hi, dim3(NB), dim3(256), 0, stream, hi, gm);
        hipLaunchKernelGGL(k_ee, dim3(NB), dim3(256), 0, stream,
                           hij, Weer + (l-1)*1024, beer + (l-1)*32, hij, eem);
        hipLaunchKernelGGL(k_fbuild, dim3(66560), dim3(256), 0, stream, hi, gm, eem, f);
        hipLaunchKernelGGL(k_gemm_hi, dim3(1280), dim3(256), 0, stream,
                           f, Wt + (l-1)*212992, ber + (l-1)*256, hi);
    }
}

// Round 6
// 811.218 us; speedup vs baseline: 1.6718x; 1.6718x over previous
//
#include <hip/hip_runtime.h>

// Problem constants (from reference setup_inputs)
#define NB   4096   // batch
#define NE   20     // electrons
#define NA   4      // atoms
#define HE   256
#define HEE  32
#define NUPC 10
#define FIN  832    // 3*HE + 2*HEE
#define IN0  56     // (3*NA+2)*(NDIM+1)

typedef short short8v __attribute__((ext_vector_type(8)));
typedef float f32x4  __attribute__((ext_vector_type(4)));

__device__ __forceinline__ float fast_tanh(float x){
    float e = __expf(-2.f*fabsf(x));
    float r = (1.f - e) / (1.f + e);
    return copysignf(r, x);
}

// fp32 -> bf16 round-to-nearest-even (bit pattern as ushort)
__device__ __forceinline__ unsigned short f2bf(float x){
    unsigned int u = __float_as_uint(x);
    u += 0x7FFFu + ((u >> 16) & 1u);
    return (unsigned short)(u >> 16);
}
__device__ __forceinline__ float bf2f(unsigned short u){
    return __uint_as_float(((unsigned)u) << 16);
}

__device__ __forceinline__ void gload16(const void* g, void* l){
    __builtin_amdgcn_global_load_lds(
        (const __attribute__((address_space(1))) void*)g,
        (__attribute__((address_space(3))) void*)l, 16, 0, 0);
}

// ---------------------------------------------------------------------------
// Convert + transpose We_rest [3][832][256] f32  ->  Wt [3][256][832] bf16
// ---------------------------------------------------------------------------
__global__ __launch_bounds__(256) void k_wconv(const float* __restrict__ W,
                                               unsigned short* __restrict__ Wt){
    int idx = blockIdx.x*256 + threadIdx.x;
    if (idx >= 3*832*256) return;
    int l = idx / (832*256);
    int rem = idx - l*(832*256);
    int k = rem >> 8, c = rem & 255;
    Wt[(size_t)l*212992 + (size_t)c*832 + k] = f2bf(W[idx]);
}

// ---------------------------------------------------------------------------
// Layer 0, h_i path only: build f0 (56 cols incl. means), apply hi linear 0.
// One block per batch element b. (ee path fully handled by k_ee_fused.)
// ---------------------------------------------------------------------------
__global__ __launch_bounds__(256) void k_layer0(
    const float* __restrict__ pos, const float* __restrict__ rnuc,
    const float* __restrict__ We0, const float* __restrict__ be0,
    float* __restrict__ hi)
{
    __shared__ float ps[NE][3];
    __shared__ float rn[NA][3];
    __shared__ float f0[NE][IN0];
    __shared__ float h0[NE][NE][4];
    int b = blockIdx.x, t = threadIdx.x;
    if (t < 60)               ps[t/3][t%3] = pos[b*60 + t];
    if (t >= 64 && t < 76)    rn[(t-64)/3][(t-64)%3] = rnuc[t-64];
    __syncthreads();
    if (t < 80){
        int n = t >> 2, a = t & 3;
        float dx = ps[n][0]-rn[a][0], dy = ps[n][1]-rn[a][1], dz = ps[n][2]-rn[a][2];
        f0[n][a*4+0] = dx; f0[n][a*4+1] = dy; f0[n][a*4+2] = dz;
        f0[n][a*4+3] = sqrtf(dx*dx + dy*dy + dz*dz);
    }
    for (int q = t; q < 400; q += 256){
        int i = q/20, j = q - 20*(q/20);
        float dx = ps[i][0]-ps[j][0], dy = ps[i][1]-ps[j][1], dz = ps[i][2]-ps[j][2];
        float sq = dx*dx + dy*dy + dz*dz;
        h0[i][j][0] = dx; h0[i][j][1] = dy; h0[i][j][2] = dz;
        h0[i][j][3] = sq > 0.f ? sqrtf(sq) : 0.f;   // _safe_norm: exact 0 when i==j
    }
    __syncthreads();
    // spin means of h_i0 -> f0 cols 16..47
    for (int q = t; q < 320; q += 256){
        int n = q >> 4, m = q & 15;
        float sd = 0.f, su = 0.f;
        #pragma unroll
        for (int i = 0; i < 10; i++)  sd += f0[i][m];
        #pragma unroll
        for (int i = 10; i < 20; i++) su += f0[i][m];
        f0[n][16+m] = sd*0.1f; f0[n][32+m] = su*0.1f;
    }
    // ee means over i -> f0 cols 48..55
    if (t < 80){
        int n = t >> 2, c = t & 3;
        float sd = 0.f, su = 0.f;
        #pragma unroll
        for (int i = 0; i < 10; i++)  sd += h0[i][n][c];
        #pragma unroll
        for (int i = 10; i < 20; i++) su += h0[i][n][c];
        f0[n][48+c] = sd*0.1f; f0[n][52+c] = su*0.1f;
    }
    __syncthreads();
    // hi linear 0: [20,56]@[56,256], tanh, no residual (56 != 256)
    {
        int c = t;
        float wcol[IN0];
        #pragma unroll
        for (int k = 0; k < IN0; k++) wcol[k] = We0[k*256 + c];
        float bias = be0[c];
        float* ob = hi + (size_t)b*5120 + c;
        for (int n = 0; n < NE; n++){
            float acc = bias;
            #pragma unroll
            for (int k = 0; k < IN0; k++) acc += f0[n][k]*wcol[k];
            ob[n*256] = fast_tanh(acc);
        }
    }
}

// ---------------------------------------------------------------------------
// Fully fused ee path: h_ij^1 = tanh(h_ij^0 @ Wee0 + bee0) computed from pos;
// then 3 layers of  eem_l = means(h^l);  h^{l+1} = tanh(h^l @ Wee_l) + h^l.
// One block (256 thr, 4 waves) per batch element. Master h in registers
// (each lane owns its MFMA C-frag elements); bf16 staging copy in LDS with
// row stride 80 B (bank-conflict-free ds_read_b128 A-frags: 20r+4q uniform
// mod 32). GEMM via mfma_f32_16x16x32_bf16 (K=32 exact, N=32 as 2 n-tiles).
// Global traffic: read pos (240 B/blk), write eem (bf16) + final h_ij (fp32).
// ---------------------------------------------------------------------------
__global__ __launch_bounds__(256) void k_ee_fused(
    const float* __restrict__ pos,
    const float* __restrict__ Wee0, const float* __restrict__ bee0,
    const float* __restrict__ Weer, const float* __restrict__ beer,
    float* __restrict__ hij, unsigned short* __restrict__ eem)
{
    __shared__ float ps[NE][4];
    __shared__ unsigned short hbf[400*40];  // [row][40] ushorts (80 B stride)
    __shared__ unsigned short Wb[32*40];    // [col][k] transposed, same stride
    int b = blockIdx.x, t = threadIdx.x;
    int wave = t >> 6, lane = t & 63;
    int rq = lane >> 4, cl = lane & 15;
    if (t < 60) ps[t/3][t%3] = pos[b*60 + t];
    __syncthreads();

    // ---- layer 0: h1 = tanh(h0 @ Wee0 + bee0), h0 built from pos on the fly
    float w0[2][4], b0[2];
    #pragma unroll
    for (int nt = 0; nt < 2; nt++){
        int c = nt*16 + cl;
        b0[nt] = bee0[c];
        #pragma unroll
        for (int k = 0; k < 4; k++) w0[nt][k] = Wee0[k*32 + c];
    }
    float hm[7][2][4];   // master h, fp32: [m-tile slot][n-tile][row-in-quad]
    #pragma unroll
    for (int s = 0; s < 7; s++){
        int mt = wave + 4*s;
        if (mt < 25){
            #pragma unroll
            for (int jj = 0; jj < 4; jj++){
                int r = mt*16 + rq*4 + jj;
                int i = r/20, j = r - (r/20)*20;
                float dx = ps[i][0]-ps[j][0];
                float dy = ps[i][1]-ps[j][1];
                float dz = ps[i][2]-ps[j][2];
                float rij = sqrtf(dx*dx + dy*dy + dz*dz);  // i==j -> exactly 0
                #pragma unroll
                for (int nt = 0; nt < 2; nt++){
                    float z = dx*w0[nt][0] + dy*w0[nt][1] + dz*w0[nt][2]
                            + rij*w0[nt][3] + b0[nt];
                    hm[s][nt][jj] = fast_tanh(z);
                }
            }
        }
    }
    // stage h1 (bf16) for MFMA + means
    #pragma unroll
    for (int s = 0; s < 7; s++){
        int mt = wave + 4*s;
        if (mt < 25){
            #pragma unroll
            for (int jj = 0; jj < 4; jj++){
                int r = mt*16 + rq*4 + jj;
                #pragma unroll
                for (int nt = 0; nt < 2; nt++)
                    hbf[r*40 + nt*16 + cl] = f2bf(hm[s][nt][jj]);
            }
        }
    }
    __syncthreads();

    // ---- layers 1..3
    for (int l = 1; l <= 3; l++){
        const float* Wl = Weer + (l-1)*1024;
        // Wb <- Wee_l transposed [c][k], bf16
        for (int p = t; p < 1024; p += 256){
            int k = p >> 5, c = p & 31;
            Wb[c*40 + k] = f2bf(Wl[p]);
        }
        // eem_l = spin means over i of h^l (pre-update), bf16 out
        unsigned short* eemL = eem + (size_t)(l-1)*NB*1280 + (size_t)b*1280;
        for (int q = t; q < 640; q += 256){
            int j = q >> 5, c = q & 31;
            float sd = 0.f, su = 0.f;
            #pragma unroll
            for (int i = 0; i < 10; i++)  sd += bf2f(hbf[(i*20+j)*40 + c]);
            #pragma unroll
            for (int i = 10; i < 20; i++) su += bf2f(hbf[(i*20+j)*40 + c]);
            eemL[j*64 + c]      = f2bf(sd*0.1f);
            eemL[j*64 + 32 + c] = f2bf(su*0.1f);
        }
        __syncthreads();
        // MFMA update: z = h^l @ Wee_l ; h^{l+1} = tanh(z+b) + h^l
        short8v bfr0 = *(const short8v*)&Wb[cl*40 + rq*8];
        short8v bfr1 = *(const short8v*)&Wb[(16+cl)*40 + rq*8];
        float bias0 = beer[(l-1)*32 + cl];
        float bias1 = beer[(l-1)*32 + 16 + cl];
        #pragma unroll
        for (int s = 0; s < 7; s++){
            int mt = wave + 4*s;
            if (mt < 25){
                short8v af = *(const short8v*)&hbf[(mt*16 + cl)*40 + rq*8];
                f32x4 zero = {0.f, 0.f, 0.f, 0.f};
                f32x4 z0 = __builtin_amdgcn_mfma_f32_16x16x32_bf16(af, bfr0, zero, 0, 0, 0);
                f32x4 z1 = __builtin_amdgcn_mfma_f32_16x16x32_bf16(af, bfr1, zero, 0, 0, 0);
                #pragma unroll
                for (int jj = 0; jj < 4; jj++){
                    hm[s][0][jj] += fast_tanh(z0[jj] + bias0);
                    hm[s][1][jj] += fast_tanh(z1[jj] + bias1);
                }
            }
        }
        __syncthreads();   // all A/B-frag reads done before hbf overwrite
        if (l < 3){
            #pragma unroll
            for (int s = 0; s < 7; s++){
                int mt = wave + 4*s;
                if (mt < 25){
                    #pragma unroll
                    for (int jj = 0; jj < 4; jj++){
                        int r = mt*16 + rq*4 + jj;
                        #pragma unroll
                        for (int nt = 0; nt < 2; nt++)
                            hbf[r*40 + nt*16 + cl] = f2bf(hm[s][nt][jj]);
                    }
                }
            }
            __syncthreads();
        }
    }
    // ---- final h_ij write (fp32)
    float* ob = hij + (size_t)b*12800;
    #pragma unroll
    for (int s = 0; s < 7; s++){
        int mt = wave + 4*s;
        if (mt < 25){
            #pragma unroll
            for (int jj = 0; jj < 4; jj++){
                int r = mt*16 + rq*4 + jj;
                #pragma unroll
                for (int nt = 0; nt < 2; nt++)
                    ob[r*32 + nt*16 + cl] = hm[s][nt][jj];
            }
        }
    }
}

// ---------------------------------------------------------------------------
// Spin means of h_i -> gm (bf16): [b][0..255]=mean(i<10), [b][256..511]=mean(i>=10)
// ---------------------------------------------------------------------------
__global__ __launch_bounds__(256) void k_means_hi(const float* __restrict__ hi,
                                                  unsigned short* __restrict__ gm){
    int b = blockIdx.x, c = threadIdx.x;
    const float* p = hi + (size_t)b*5120 + c;
    float sd = 0.f, su = 0.f;
    #pragma unroll
    for (int i = 0; i < 10; i++)  sd += p[i*256];
    #pragma unroll
    for (int i = 10; i < 20; i++) su += p[i*256];
    gm[b*512 + c]       = f2bf(sd*0.1f);
    gm[b*512 + 256 + c] = f2bf(su*0.1f);
}

// ---------------------------------------------------------------------------
// Per-batch broadcast term: v[b][c] = sum_k gm[b][k] * W[256+k][c] + be[c].
// (g_down/g_up are constant over the 20 rows of a batch, so their 512 of 832
// K-columns factor out of the big GEMM.)  M=4096, K=512, N=256 bf16 MFMA.
// A = gm [4096][512] bf16, B = Wt[c][256..767]. Grid 64 blocks.
// ---------------------------------------------------------------------------
__global__ __launch_bounds__(256) void k_gmv(
    const unsigned short* __restrict__ gm, const unsigned short* __restrict__ Wt,
    const float* __restrict__ be, float* __restrict__ v)
{
    __shared__ unsigned short As[128*32];
    __shared__ unsigned short Bs[128*32];
    int t = threadIdx.x;
    int wave = t >> 6, lane = t & 63;
    int mtile = blockIdx.x >> 1, ntile = blockIdx.x & 1;
    int wr = wave >> 1, wc = wave & 1;
    f32x4 acc[4][4] = {};
    const unsigned short* abase = gm + (size_t)mtile*128*512;
    const unsigned short* wbase = Wt + (size_t)ntile*128*832;
    int off0 = wave*1024 + lane*16;
    int rl = lane & 15, kq = (lane >> 4)*8;
    for (int ks = 0; ks < 16; ks++){
        int kb = ks*32;
        #pragma unroll
        for (int q = 0; q < 2; q++){
            int off = off0 + q*4096;
            int row = off >> 6, ch = (off & 63) >> 4;
            gload16(abase + (size_t)row*512 + kb + ch*8,       (char*)As + off);
            gload16(wbase + (size_t)row*832 + 256 + kb + ch*8, (char*)Bs + off);
        }
        asm volatile("s_waitcnt vmcnt(0)" ::: "memory");
        __syncthreads();
        short8v af[4], bfr[4];
        #pragma unroll
        for (int m = 0; m < 4; m++)
            af[m] = *(const short8v*)(As + (wr*64 + m*16 + rl)*32 + kq);
        #pragma unroll
        for (int n = 0; n < 4; n++)
            bfr[n] = *(const short8v*)(Bs + (wc*64 + n*16 + rl)*32 + kq);
        #pragma unroll
        for (int m = 0; m < 4; m++)
            #pragma unroll
            for (int n = 0; n < 4; n++)
                acc[m][n] = __builtin_amdgcn_mfma_f32_16x16x32_bf16(af[m], bfr[n], acc[m][n], 0, 0, 0);
        __syncthreads();
    }
    int rq = lane >> 4;
    #pragma unroll
    for (int m = 0; m < 4; m++){
        int rowb = mtile*128 + wr*64 + m*16 + rq*4;
        #pragma unroll
        for (int n = 0; n < 4; n++){
            int col = ntile*128 + wc*64 + n*16 + rl;
            float bias = be[col];
            #pragma unroll
            for (int r = 0; r < 4; r++)
                v[(size_t)(rowb + r)*256 + col] = acc[m][n][r] + bias;
        }
    }
}

// ---------------------------------------------------------------------------
// Build compact f' (bf16) rows: [h_i (256) | eem_dn (32) | eem_up (32)] = 320
// cols.  eem[b][n][0..63] is exactly the last 64 cols (already bf16).
// ---------------------------------------------------------------------------
__global__ __launch_bounds__(256) void k_fbuild(const float* __restrict__ hi,
    const unsigned short* __restrict__ eem, unsigned short* __restrict__ f)
{
    int idx = blockIdx.x*256 + threadIdx.x;   // 81920*80 total, grid exact
    int rw = idx / 80, c4 = idx - rw*80;
    int k0 = c4*4;
    uint2 o;
    if (k0 < 256){
        float4 vv = *(const float4*)(hi + (size_t)rw*256 + k0);
        o.x = (unsigned)f2bf(vv.x) | ((unsigned)f2bf(vv.y) << 16);
        o.y = (unsigned)f2bf(vv.z) | ((unsigned)f2bf(vv.w) << 16);
    } else {
        int b = rw / 20, n = rw - b*20;
        o = *(const uint2*)(eem + (size_t)b*1280 + n*64 + (k0-256));
    }
    *(uint2*)(f + (size_t)idx*4) = o;
}

// ---------------------------------------------------------------------------
// Main GEMM (layers 1..3): h_i = tanh(f' @ W' + v[b]) + h_i
// M=81920, K=320 (=256 h_i cols + 64 eem cols), N=256. bf16 MFMA 16x16x32,
// 128x128 tile, BK=32, 4 waves of 64x64.  B k-mapping: ks<8 -> Wt k=ks*32
// (W1), ks 8..9 -> Wt k=768+(ks-8)*32 (W4).  v[b] carries be + gm@W23.
// ---------------------------------------------------------------------------
__global__ __launch_bounds__(256) void k_gemm_hi(
    const unsigned short* __restrict__ f, const unsigned short* __restrict__ Wt,
    const float* __restrict__ v, float* __restrict__ hi)
{
    __shared__ unsigned short As[128*32];   // [row][k] 8KB
    __shared__ unsigned short Bs[128*32];   // [col][k] 8KB
    int t = threadIdx.x;
    int wave = t >> 6, lane = t & 63;
    int mtile = blockIdx.x >> 1, ntile = blockIdx.x & 1;
    int wr = wave >> 1, wc = wave & 1;
    f32x4 acc[4][4] = {};
    const unsigned short* fbase = f  + (size_t)mtile*128*320;
    const unsigned short* wbase = Wt + (size_t)ntile*128*832;
    int off0 = wave*1024 + lane*16;         // byte offset pattern for staging
    int rl = lane & 15, kq = (lane >> 4)*8;
    for (int ks = 0; ks < 10; ks++){
        int kbA = ks*32;
        int kbB = ks < 8 ? ks*32 : 768 + (ks-8)*32;
        #pragma unroll
        for (int q = 0; q < 2; q++){
            int off = off0 + q*4096;
            int row = off >> 6, ch = (off & 63) >> 4;
            gload16(fbase + (size_t)row*320 + kbA + ch*8, (char*)As + off);
            gload16(wbase + (size_t)row*832 + kbB + ch*8, (char*)Bs + off);
        }
        asm volatile("s_waitcnt vmcnt(0)" ::: "memory");
        __syncthreads();
        short8v af[4], bfr[4];
        #pragma unroll
        for (int m = 0; m < 4; m++)
            af[m] = *(const short8v*)(As + (wr*64 + m*16 + rl)*32 + kq);
        #pragma unroll
        for (int n = 0; n < 4; n++)
            bfr[n] = *(const short8v*)(Bs + (wc*64 + n*16 + rl)*32 + kq);
        #pragma unroll
        for (int m = 0; m < 4; m++)
            #pragma unroll
            for (int n = 0; n < 4; n++)
                acc[m][n] = __builtin_amdgcn_mfma_f32_16x16x32_bf16(af[m], bfr[n], acc[m][n], 0, 0, 0);
        __syncthreads();
    }
    // epilogue: C/D layout col=lane&15, row=(lane>>4)*4+r ; z += v[row/20]
    int rq = lane >> 4;
    #pragma unroll
    for (int m = 0; m < 4; m++){
        int rowb = mtile*128 + wr*64 + m*16 + rq*4;
        #pragma unroll
        for (int n = 0; n < 4; n++){
            int col = ntile*128 + wc*64 + n*16 + rl;
            #pragma unroll
            for (int r = 0; r < 4; r++){
                int grow = rowb + r;
                int bb = grow / 20;
                size_t o = (size_t)grow*256 + col;
                float z = acc[m][n][r] + v[(size_t)bb*256 + col];
                hi[o] = fast_tanh(z) + hi[o];   // residual, in-place
            }
        }
    }
}

// ---------------------------------------------------------------------------
extern "C" void kernel_launch(void* const* d_in, const int* in_sizes, int n_in,
                              void* d_out, int out_size, void* d_ws, size_t ws_size,
                              hipStream_t stream)
{
    const float* pos  = (const float*)d_in[0];
    const float* rnuc = (const float*)d_in[1];
    const float* We0  = (const float*)d_in[2];
    const float* be0  = (const float*)d_in[3];
    const float* Wer  = (const float*)d_in[4];   // [3][832][256]
    const float* ber  = (const float*)d_in[5];   // [3][256]
    const float* Wee0 = (const float*)d_in[6];
    const float* bee0 = (const float*)d_in[7];
    const float* Weer = (const float*)d_in[8];   // [3][32][32]
    const float* beer = (const float*)d_in[9];   // [3][32]

    float* hi  = (float*)d_out;                     // [81920][256]
    float* hij = (float*)d_out + (size_t)81920*256; // [4096][20][20][32]

    char* w = (char*)d_ws;
    unsigned short* gm  = (unsigned short*)w;                 // 4096*512*2    =  4,194,304 B
    unsigned short* eem = (unsigned short*)(w + 4194304);     // 3*4096*1280*2 = 31,457,280 B
    float*          v   = (float*)(w + 35651584);             // 4096*256*4    =  4,194,304 B
    unsigned short* f   = (unsigned short*)(w + 39845888);    // 81920*320*2   = 52,428,800 B
    unsigned short* Wt  = (unsigned short*)(w + 92274688);    // 3*256*832*2   =  1,277,952 B

    hipLaunchKernelGGL(k_wconv, dim3(2496), dim3(256), 0, stream, Wer, Wt);
    hipLaunchKernelGGL(k_layer0, dim3(NB), dim3(256), 0, stream,
                       pos, rnuc, We0, be0, hi);
    hipLaunchKernelGGL(k_ee_fused, dim3(NB), dim3(256), 0, stream,
                       pos, Wee0, bee0, Weer, beer, hij, eem);
    for (int l = 1; l < 4; l++){
        hipLaunchKernelGGL(k_means_hi, dim3(NB), dim3(256), 0, stream, hi, gm);
        hipLaunchKernelGGL(k_gmv, dim3(64), dim3(256), 0, stream,
                           gm, Wt + (l-1)*212992, ber + (l-1)*256, v);
        hipLaunchKernelGGL(k_fbuild, dim3(25600), dim3(256), 0, stream,
                           hi, eem + (size_t)(l-1)*NB*1280, f);
        hipLaunchKernelGGL(k_gemm_hi, dim3(1280), dim3(256), 0, stream,
                           f, Wt + (l-1)*212992, v, hi);
    }
}